// Round 6
// baseline (239.097 us; speedup 1.0000x reference)
//
#include <hip/hip_runtime.h>
#include <hip/hip_bf16.h>
#include <hip/hip_fp8.h>

typedef unsigned char u8;
typedef __attribute__((ext_vector_type(4))) float f32x4;

#define NROWS 8192   // B*N = 128*64
#define DDIM  256    // feature dim
#define NBLK  2080   // 64*65/2 triangular tiles

// ---------------- Kernel 1: L2-normalize rows, f32 -> fp8 e4m3 (+ zero acc/counter) ----
__global__ __launch_bounds__(256) void norm_kernel(const float* __restrict__ in,
                                                   u8* __restrict__ out,
                                                   float* __restrict__ acc0,
                                                   int* __restrict__ counter) {
    int tid = threadIdx.x;
    if (blockIdx.x < 64) acc0[blockIdx.x * 256 + tid] = 0.f;  // zero tot+pos (16384 f32)
    if (blockIdx.x == 64 && tid == 0) *counter = 0;
    int wave = tid >> 6, lane = tid & 63;
    int row = blockIdx.x * 4 + wave;                 // 2048 blocks * 4 rows
    float4 v = ((const float4*)(in + (size_t)row * DDIM))[lane];
    float ss = v.x * v.x + v.y * v.y + v.z * v.z + v.w * v.w;
    #pragma unroll
    for (int m = 1; m < 64; m <<= 1) ss += __shfl_xor(ss, m, 64);
    float sc = 1.0f / fmaxf(sqrtf(ss), 1e-12f);
    __hip_fp8_e4m3 q0(v.x * sc), q1(v.y * sc), q2(v.z * sc), q3(v.w * sc);
    unsigned pk = (unsigned)q0.__x | ((unsigned)q1.__x << 8) |
                  ((unsigned)q2.__x << 16) | ((unsigned)q3.__x << 24);
    ((unsigned*)out)[row * 64 + lane] = pk;          // 4 fp8 bytes per lane
}

// ---------------- Kernel 2: fused Gram + exp + row/col-sum + tail loss ----------------
// 2080 blocks = tiles (ti<=tj) of 128x128. fp8 e4m3, FULL K=256 in LDS at once:
// A-panel 32KB + B-panel 32KB -> ONE barrier, then 8 straight-line k-steps
// (16x16x32 fp8 MFMA), zero inner barriers. 16B-chunk XOR swizzle (r&7)<<4 with
// inverse-swizzled global source (rule 21); ds_read_b64 stays in its chunk -> 2-way max.
// Last block (device-scope counter) computes the final loss (saves a launch).
__global__ __launch_bounds__(256) void sim_kernel(const u8* __restrict__ f8,
                                                  float* __restrict__ tot_acc,
                                                  float* __restrict__ pos_acc,
                                                  int* __restrict__ counter,
                                                  float* __restrict__ out) {
    __shared__ u8 lA[128 * 256];   // 32 KB
    __shared__ u8 lB[128 * 256];   // 32 KB
    __shared__ float red[4];
    __shared__ int lastflag;

    const int tid  = threadIdx.x;
    const int lane = tid & 63;
    const int wave = tid >> 6;
    const int wr = wave >> 1, wc = wave & 1;

    // XCD-chunked bijective swizzle (T1): 2080 = 8*260
    int k = (blockIdx.x & 7) * 260 + (blockIdx.x >> 3);
    // decode k -> (ti, tj), ti <= tj
    int a = (int)((sqrtf(8.f * (float)k + 1.f) - 1.f) * 0.5f);
    while ((a + 1) * (a + 2) / 2 <= k) ++a;
    while (a * (a + 1) / 2 > k) --a;
    const int ti = k - a * (a + 1) / 2;
    const int tj = a;
    const int brow = ti * 128, bcol = tj * 128;

    // ---- one-shot staging: both full-K panels, 16 chunks/thread ----
    #pragma unroll
    for (int i = 0; i < 8; ++i) {
        int o   = (i * 256 + tid) * 16;     // linear LDS byte offset (row-major [128][256])
        int r   = o >> 8;
        int cb  = o & 255;
        int scb = cb ^ ((r & 7) << 4);      // inverse-swizzled SOURCE column byte
        const u8* gA = f8 + (size_t)(brow + r) * DDIM + scb;
        __builtin_amdgcn_global_load_lds(
            (const __attribute__((address_space(1))) void*)gA,
            (__attribute__((address_space(3))) void*)(lA + o), 16, 0, 0);
        const u8* gB = f8 + (size_t)(bcol + r) * DDIM + scb;
        __builtin_amdgcn_global_load_lds(
            (const __attribute__((address_space(1))) void*)gB,
            (__attribute__((address_space(3))) void*)(lB + o), 16, 0, 0);
    }

    f32x4 acc[4][4];
    #pragma unroll
    for (int m = 0; m < 4; ++m)
        #pragma unroll
        for (int n = 0; n < 4; ++n)
            acc[m][n] = (f32x4){0.f, 0.f, 0.f, 0.f};

    __syncthreads();   // the ONLY barrier before compute (drains vmcnt)

    // ---- 8 straight-line k-steps, no barriers ----
    #pragma unroll
    for (int s = 0; s < 8; ++s) {
        long av[4], bv[4];
        const int ob = s * 32 + ((lane >> 4) << 3);   // this lane-group's 8 k-bytes
        #pragma unroll
        for (int m = 0; m < 4; ++m) {
            int rA = wr * 64 + m * 16 + (lane & 15);
            av[m] = *(const long*)(lA + rA * 256 + (ob ^ ((rA & 7) << 4)));
            int rB = wc * 64 + m * 16 + (lane & 15);
            bv[m] = *(const long*)(lB + rB * 256 + (ob ^ ((rB & 7) << 4)));
        }
        #pragma unroll
        for (int m = 0; m < 4; ++m)
            #pragma unroll
            for (int n = 0; n < 4; ++n)
                acc[m][n] = __builtin_amdgcn_mfma_f32_16x16x32_fp8_fp8(av[m], bv[n], acc[m][n], 0, 0, 0);
    }

    // ---- epilogue: exp, row sums (+ col sums off-diag) ----
    // C layout: col = lane&15, row = (lane>>4)*4 + j  (shape-determined, m89/m121-128)
    #pragma unroll
    for (int m = 0; m < 4; ++m)
        #pragma unroll
        for (int n = 0; n < 4; ++n)
            #pragma unroll
            for (int j = 0; j < 4; ++j)
                acc[m][n][j] = __expf(acc[m][n][j]);

    float rs[4][4];
    #pragma unroll
    for (int m = 0; m < 4; ++m)
        #pragma unroll
        for (int j = 0; j < 4; ++j) {
            float s = acc[m][0][j] + acc[m][1][j] + acc[m][2][j] + acc[m][3][j];
            s += __shfl_xor(s, 1, 64);
            s += __shfl_xor(s, 2, 64);
            s += __shfl_xor(s, 4, 64);
            s += __shfl_xor(s, 8, 64);
            rs[m][j] = s;
        }

    if (ti == tj) {
        const bool diag = (wr == wc);           // batch blocks are 64-aligned
        if ((lane & 15) == 0) {
            const int g = lane >> 4;
            #pragma unroll
            for (int m = 0; m < 4; ++m)
                #pragma unroll
                for (int j = 0; j < 4; ++j) {
                    int row = brow + wr * 64 + m * 16 + g * 4 + j;
                    float v = rs[m][j];
                    atomicAdd(&tot_acc[row], v);
                    if (diag) atomicAdd(&pos_acc[row], v);
                }
        }
    } else {
        float cs[4];
        #pragma unroll
        for (int n = 0; n < 4; ++n) {
            float s = 0.f;
            #pragma unroll
            for (int m = 0; m < 4; ++m)
                #pragma unroll
                for (int j = 0; j < 4; ++j) s += acc[m][n][j];
            s += __shfl_xor(s, 16, 64);
            s += __shfl_xor(s, 32, 64);
            cs[n] = s;
        }
        if ((lane & 15) == 0) {
            const int g = lane >> 4;
            #pragma unroll
            for (int m = 0; m < 4; ++m)
                #pragma unroll
                for (int j = 0; j < 4; ++j)
                    atomicAdd(&tot_acc[brow + wr * 64 + m * 16 + g * 4 + j], rs[m][j]);
        }
        if (lane < 16) {
            #pragma unroll
            for (int n = 0; n < 4; ++n)
                atomicAdd(&tot_acc[bcol + wc * 64 + n * 16 + lane], cs[n]);
        }
    }

    // ---- last block computes the loss (device-scope handoff) ----
    __threadfence();
    __syncthreads();
    if (tid == 0) {
        int prev = __hip_atomic_fetch_add(counter, 1, __ATOMIC_ACQ_REL, __HIP_MEMORY_SCOPE_AGENT);
        lastflag = (prev == NBLK - 1);
    }
    __syncthreads();
    if (lastflag) {
        float s = 0.f;
        for (int r = tid; r < NROWS; r += 256) {
            float tv = __hip_atomic_load(&tot_acc[r], __ATOMIC_RELAXED, __HIP_MEMORY_SCOPE_AGENT);
            float pv = __hip_atomic_load(&pos_acc[r], __ATOMIC_RELAXED, __HIP_MEMORY_SCOPE_AGENT);
            s += logf(tv) - logf(pv);
        }
        #pragma unroll
        for (int m = 1; m < 64; m <<= 1) s += __shfl_xor(s, m, 64);
        if ((tid & 63) == 0) red[tid >> 6] = s;
        __syncthreads();
        if (tid == 0)
            out[0] = (red[0] + red[1] + red[2] + red[3]) * (1.0f / (float)NROWS);
    }
}

extern "C" void kernel_launch(void* const* d_in, const int* in_sizes, int n_in,
                              void* d_out, int out_size, void* d_ws, size_t ws_size,
                              hipStream_t stream) {
    const float* feat = (const float*)d_in[0];
    u8*    f8   = (u8*)d_ws;                                    // 8192*256 = 2 MB
    float* tot  = (float*)((char*)d_ws + (size_t)NROWS * DDIM); // +2 MB
    float* pos  = tot + NROWS;
    int*   ctr  = (int*)(pos + NROWS);
    norm_kernel<<<dim3(NROWS / 4), dim3(256), 0, stream>>>(feat, f8, tot, ctr);
    sim_kernel<<<dim3(NBLK), dim3(256), 0, stream>>>(f8, tot, pos, ctr, (float*)d_out);
}

// Round 7
// 98.156 us; speedup vs baseline: 2.4359x; 2.4359x over previous
//
#include <hip/hip_runtime.h>
#include <hip/hip_bf16.h>
#include <hip/hip_fp8.h>

typedef unsigned char u8;
typedef __attribute__((ext_vector_type(4))) float f32x4;
typedef __attribute__((ext_vector_type(4))) int   i32x4;
typedef __attribute__((ext_vector_type(8))) int   i32x8;

#define NROWS 8192   // B*N = 128*64
#define DDIM  256    // feature dim
#define NBLK  2080   // 64*65/2 triangular 128x128 tiles
#define GRID  512    // persistent blocks (2 per CU)

// ---------------- Kernel 1: L2-normalize rows, f32 -> fp8 e4m3 (+ zero accumulators) ----
__global__ __launch_bounds__(256) void norm_kernel(const float* __restrict__ in,
                                                   u8* __restrict__ out,
                                                   float* __restrict__ acc0) {
    int tid = threadIdx.x;
    if (blockIdx.x < 64) acc0[blockIdx.x * 256 + tid] = 0.f;  // zero tot+pos (16384 f32)
    int wave = tid >> 6, lane = tid & 63;
    int row = blockIdx.x * 4 + wave;                 // 2048 blocks * 4 rows
    float4 v = ((const float4*)(in + (size_t)row * DDIM))[lane];
    float ss = v.x * v.x + v.y * v.y + v.z * v.z + v.w * v.w;
    #pragma unroll
    for (int m = 1; m < 64; m <<= 1) ss += __shfl_xor(ss, m, 64);
    float sc = 1.0f / fmaxf(sqrtf(ss), 1e-12f);
    __hip_fp8_e4m3 q0(v.x * sc), q1(v.y * sc), q2(v.z * sc), q3(v.w * sc);
    unsigned pk = (unsigned)q0.__x | ((unsigned)q1.__x << 8) |
                  ((unsigned)q2.__x << 16) | ((unsigned)q3.__x << 24);
    ((unsigned*)out)[row * 64 + lane] = pk;          // 4 fp8 bytes per lane
}

// ---------------- Kernel 2: persistent fused Gram + exp + row/col-sum ----------------
// 512 persistent blocks; block b owns tiles k = (b&7)*260 + (b>>3) + i*64 (XCD-chunked).
// Per tile: 2 K-chunks of 128 (fp8). LDS double-buffer (4 x 16 KB = 64 KB).
// Pipeline (R4-proven scheme): STAGE(next chunk) issued BEFORE compute(cur chunk);
// ONE __syncthreads per chunk (drains vmcnt + protects LDS).
// MFMA: mfma_scale_f32_16x16x128_f8f6f4 with unit scales (e8m0 0x7f = 2^0).
// Swizzle (rule 21): linear LDS dest, inverse-swizzled global source, XOR (r&7)<<4 on read
// -> the R3-measured conflict-free b128 pattern.
__device__ inline void decode_tile(int k, int& ti, int& tj) {
    int a = (int)((sqrtf(8.f * (float)k + 1.f) - 1.f) * 0.5f);
    while ((a + 1) * (a + 2) / 2 <= k) ++a;
    while (a * (a + 1) / 2 > k) --a;
    ti = k - a * (a + 1) / 2;  // row tile
    tj = a;                    // col tile, ti <= tj
}

__global__ __launch_bounds__(256) void sim_kernel(const u8* __restrict__ f8,
                                                  float* __restrict__ tot_acc,
                                                  float* __restrict__ pos_acc) {
    __shared__ u8 lA[2][128 * 128];   // 2 x 16 KB
    __shared__ u8 lB[2][128 * 128];   // 2 x 16 KB  (64 KB total)

    const int tid  = threadIdx.x;
    const int lane = tid & 63;
    const int wave = tid >> 6;
    const int wr = wave >> 1, wc = wave & 1;

    const int xcd  = blockIdx.x & 7;
    const int slot = blockIdx.x >> 3;            // 0..63
    const int ntiles = (slot < 4) ? 5 : 4;       // w = slot + i*64 < 260
    const int nchunks = 2 * ntiles;
    const int kbase0 = xcd * 260 + slot;

    // stage one K-chunk (A rows brow..brow+127, B rows bcol.., k-bytes kc..kc+127)
    #define STAGE(bufsel, bro, bco, kc)                                              \
        {                                                                            \
            _Pragma("unroll")                                                        \
            for (int i = 0; i < 4; ++i) {                                            \
                int o   = (i * 256 + tid) * 16;   /* linear LDS byte offset */       \
                int r   = o >> 7;                 /* row (128 B per row) */          \
                int cb  = o & 127;                                                   \
                int scb = cb ^ ((r & 7) << 4);    /* inverse-swizzled source */      \
                const u8* gA = f8 + (size_t)((bro) + r) * DDIM + (kc) + scb;         \
                __builtin_amdgcn_global_load_lds(                                    \
                    (const __attribute__((address_space(1))) void*)gA,               \
                    (__attribute__((address_space(3))) void*)(&lA[bufsel][0] + o),   \
                    16, 0, 0);                                                       \
                const u8* gB = f8 + (size_t)((bco) + r) * DDIM + (kc) + scb;         \
                __builtin_amdgcn_global_load_lds(                                    \
                    (const __attribute__((address_space(1))) void*)gB,               \
                    (__attribute__((address_space(3))) void*)(&lB[bufsel][0] + o),   \
                    16, 0, 0);                                                       \
            }                                                                        \
        }

    f32x4 acc[4][4];
    #pragma unroll
    for (int m = 0; m < 4; ++m)
        #pragma unroll
        for (int n = 0; n < 4; ++n)
            acc[m][n] = (f32x4){0.f, 0.f, 0.f, 0.f};

    int ti, tj, nti = 0, ntj = 0;
    decode_tile(kbase0, ti, tj);
    STAGE(0, ti * 128, tj * 128, 0);
    __syncthreads();

    const int kb = (lane >> 4) << 5;   // this lane-group's 32 k-bytes start

    for (int c = 0; c < nchunks; ++c) {
        // ---- issue next chunk's stage (no waits) ----
        if (c + 1 < nchunks) {
            if ((c + 1) & 1) {
                STAGE((c + 1) & 1, ti * 128, tj * 128, 128);     // 2nd half of cur tile
            } else {
                decode_tile(kbase0 + ((c + 1) >> 1) * 64, nti, ntj);
                STAGE((c + 1) & 1, nti * 128, ntj * 128, 0);     // next tile, 1st half
            }
        }

        // ---- compute current chunk: 8 fragment loads + 16 MX MFMAs ----
        const u8* bA = &lA[c & 1][0];
        const u8* bB = &lB[c & 1][0];
        i32x8 av[4], bv[4];
        #pragma unroll
        for (int m = 0; m < 4; ++m) {
            int rA = wr * 64 + m * 16 + (lane & 15);
            int sw = (rA & 7) << 4;
            const u8* p = bA + rA * 128;
            i32x4 lo = *(const i32x4*)(p + (kb ^ sw));
            i32x4 hi = *(const i32x4*)(p + ((kb + 16) ^ sw));
            av[m][0] = lo[0]; av[m][1] = lo[1]; av[m][2] = lo[2]; av[m][3] = lo[3];
            av[m][4] = hi[0]; av[m][5] = hi[1]; av[m][6] = hi[2]; av[m][7] = hi[3];
        }
        #pragma unroll
        for (int n = 0; n < 4; ++n) {
            int rB = wc * 64 + n * 16 + (lane & 15);
            int sw = (rB & 7) << 4;
            const u8* p = bB + rB * 128;
            i32x4 lo = *(const i32x4*)(p + (kb ^ sw));
            i32x4 hi = *(const i32x4*)(p + ((kb + 16) ^ sw));
            bv[n][0] = lo[0]; bv[n][1] = lo[1]; bv[n][2] = lo[2]; bv[n][3] = lo[3];
            bv[n][4] = hi[0]; bv[n][5] = hi[1]; bv[n][6] = hi[2]; bv[n][7] = hi[3];
        }
        #pragma unroll
        for (int m = 0; m < 4; ++m)
            #pragma unroll
            for (int n = 0; n < 4; ++n)
                acc[m][n] = __builtin_amdgcn_mfma_scale_f32_16x16x128_f8f6f4(
                    av[m], bv[n], acc[m][n],
                    0, 0,                 // cbsz=FP8(e4m3), blgp=FP8(e4m3)
                    0, 0x7f7f7f7f,        // A scale: opsel 0, e8m0 127 -> x1
                    0, 0x7f7f7f7f);       // B scale: x1

        // ---- tile finished? epilogue + reset ----
        if (c & 1) {
            const int brow = ti * 128, bcol = tj * 128;
            // C layout: col = lane&15, row = (lane>>4)*4 + j (shape-determined)
            #pragma unroll
            for (int m = 0; m < 4; ++m)
                #pragma unroll
                for (int n = 0; n < 4; ++n)
                    #pragma unroll
                    for (int j = 0; j < 4; ++j)
                        acc[m][n][j] = __expf(acc[m][n][j]);

            float rs[4][4];
            #pragma unroll
            for (int m = 0; m < 4; ++m)
                #pragma unroll
                for (int j = 0; j < 4; ++j) {
                    float s = acc[m][0][j] + acc[m][1][j] + acc[m][2][j] + acc[m][3][j];
                    s += __shfl_xor(s, 1, 64);
                    s += __shfl_xor(s, 2, 64);
                    s += __shfl_xor(s, 4, 64);
                    s += __shfl_xor(s, 8, 64);
                    rs[m][j] = s;
                }

            if (ti == tj) {
                const bool diag = (wr == wc);       // batch blocks are 64-aligned
                if ((lane & 15) == 0) {
                    const int g = lane >> 4;
                    #pragma unroll
                    for (int m = 0; m < 4; ++m)
                        #pragma unroll
                        for (int j = 0; j < 4; ++j) {
                            int row = brow + wr * 64 + m * 16 + g * 4 + j;
                            float v = rs[m][j];
                            atomicAdd(&tot_acc[row], v);
                            if (diag) atomicAdd(&pos_acc[row], v);
                        }
                }
            } else {
                float cs[4];
                #pragma unroll
                for (int n = 0; n < 4; ++n) {
                    float s = 0.f;
                    #pragma unroll
                    for (int m = 0; m < 4; ++m)
                        #pragma unroll
                        for (int j = 0; j < 4; ++j) s += acc[m][n][j];
                    s += __shfl_xor(s, 16, 64);
                    s += __shfl_xor(s, 32, 64);
                    cs[n] = s;
                }
                if ((lane & 15) == 0) {
                    const int g = lane >> 4;
                    #pragma unroll
                    for (int m = 0; m < 4; ++m)
                        #pragma unroll
                        for (int j = 0; j < 4; ++j)
                            atomicAdd(&tot_acc[brow + wr * 64 + m * 16 + g * 4 + j], rs[m][j]);
                }
                if (lane < 16) {
                    #pragma unroll
                    for (int n = 0; n < 4; ++n)
                        atomicAdd(&tot_acc[bcol + wc * 64 + n * 16 + lane], cs[n]);
                }
            }
            // reset for next tile
            #pragma unroll
            for (int m = 0; m < 4; ++m)
                #pragma unroll
                for (int n = 0; n < 4; ++n)
                    acc[m][n] = (f32x4){0.f, 0.f, 0.f, 0.f};
            ti = nti; tj = ntj;
        }
        __syncthreads();   // all waves done reading buf[c&1]; next stage drained
    }
    #undef STAGE
}

// ---------------- Kernel 3: loss = mean(log(total) - log(pos)) ----------------
__global__ __launch_bounds__(256) void loss_kernel(const float* __restrict__ tot,
                                                   const float* __restrict__ pos,
                                                   float* __restrict__ out) {
    __shared__ float red[4];
    int tid = threadIdx.x;
    float s = 0.f;
    for (int r = tid; r < NROWS; r += 256)
        s += logf(tot[r]) - logf(pos[r]);
    #pragma unroll
    for (int m = 1; m < 64; m <<= 1) s += __shfl_xor(s, m, 64);
    if ((tid & 63) == 0) red[tid >> 6] = s;
    __syncthreads();
    if (tid == 0)
        out[0] = (red[0] + red[1] + red[2] + red[3]) * (1.0f / (float)NROWS);
}

extern "C" void kernel_launch(void* const* d_in, const int* in_sizes, int n_in,
                              void* d_out, int out_size, void* d_ws, size_t ws_size,
                              hipStream_t stream) {
    const float* feat = (const float*)d_in[0];
    u8*    f8   = (u8*)d_ws;                                    // 8192*256 = 2 MB
    float* tot  = (float*)((char*)d_ws + (size_t)NROWS * DDIM); // +2 MB
    float* pos  = tot + NROWS;
    norm_kernel<<<dim3(NROWS / 4), dim3(256), 0, stream>>>(feat, f8, tot);
    sim_kernel<<<dim3(GRID), dim3(256), 0, stream>>>(f8, tot, pos);
    loss_kernel<<<dim3(1), dim3(256), 0, stream>>>(tot, pos, (float*)d_out);
}

// Round 9
// 91.099 us; speedup vs baseline: 2.6246x; 1.0775x over previous
//
#include <hip/hip_runtime.h>
#include <hip/hip_bf16.h>
#include <hip/hip_fp8.h>

typedef unsigned char u8;
typedef __attribute__((ext_vector_type(4))) float f32x4;
typedef __attribute__((ext_vector_type(4))) int   i32x4;
typedef __attribute__((ext_vector_type(8))) int   i32x8;

#define NROWS 8192   // B*N = 128*64
#define DDIM  256    // feature dim
#define NBLK  2080   // 64*65/2 triangular 128x128 tiles
#define GRID  512    // persistent blocks (2 per CU)

// ---------------- Kernel 1: L2-normalize rows, f32 -> fp8 e4m3 (+ zero accumulators) ----
__global__ __launch_bounds__(256) void norm_kernel(const float* __restrict__ in,
                                                   u8* __restrict__ out,
                                                   float* __restrict__ acc0) {
    int tid = threadIdx.x;
    if (blockIdx.x < 64) acc0[blockIdx.x * 256 + tid] = 0.f;  // zero tot+pos (16384 f32)
    int wave = tid >> 6, lane = tid & 63;
    int row = blockIdx.x * 4 + wave;                 // 2048 blocks * 4 rows
    float4 v = ((const float4*)(in + (size_t)row * DDIM))[lane];
    float ss = v.x * v.x + v.y * v.y + v.z * v.z + v.w * v.w;
    #pragma unroll
    for (int m = 1; m < 64; m <<= 1) ss += __shfl_xor(ss, m, 64);
    float sc = 1.0f / fmaxf(sqrtf(ss), 1e-12f);
    __hip_fp8_e4m3 q0(v.x * sc), q1(v.y * sc), q2(v.z * sc), q3(v.w * sc);
    unsigned pk = (unsigned)q0.__x | ((unsigned)q1.__x << 8) |
                  ((unsigned)q2.__x << 16) | ((unsigned)q3.__x << 24);
    ((unsigned*)out)[row * 64 + lane] = pk;          // 4 fp8 bytes per lane
}

// ---------------- Kernel 2: persistent fused Gram + exp + row/col-sum ----------------
// 512 persistent blocks; block b owns tiles k = (b&7)*260 + (b>>3) + i*64 (XCD-chunked).
// Per tile: 2 K-chunks of 128 (fp8). LDS double-buffer (4 x 16 KB = 64 KB).
// TRUE pipeline (T4 counted vmcnt, m201-style): per chunk
//   STAGE(c+1)  [8 global_load_lds per wave]
//   s_waitcnt vmcnt(8)    <- waits chunk c's loads only; c+1's stay in flight
//   s_barrier             <- all waves see buf[c] complete
//   compute(c)            <- ds_read + MFMA while c+1 loads fly
//   s_barrier             <- all waves done reading buf[c] before it's restaged
// MFMA: mfma_scale_f32_16x16x128_f8f6f4 with unit scales (e8m0 0x7f = 2^0).
// Swizzle (rule 21): linear LDS dest, inverse-swizzled global source, XOR (r&7)<<4 on read.
__device__ inline void decode_tile(int k, int& ti, int& tj) {
    int a = (int)((sqrtf(8.f * (float)k + 1.f) - 1.f) * 0.5f);
    while ((a + 1) * (a + 2) / 2 <= k) ++a;
    while (a * (a + 1) / 2 > k) --a;
    ti = k - a * (a + 1) / 2;  // row tile
    tj = a;                    // col tile, ti <= tj
}

#define CFENCE asm volatile("" ::: "memory")

__global__ __launch_bounds__(256) void sim_kernel(const u8* __restrict__ f8,
                                                  float* __restrict__ tot_acc,
                                                  float* __restrict__ pos_acc) {
    __shared__ u8 lA[2][128 * 128];   // 2 x 16 KB
    __shared__ u8 lB[2][128 * 128];   // 2 x 16 KB  (64 KB total)

    const int tid  = threadIdx.x;
    const int lane = tid & 63;
    const int wave = tid >> 6;
    const int wr = wave >> 1, wc = wave & 1;

    const int xcd  = blockIdx.x & 7;
    const int slot = blockIdx.x >> 3;            // 0..63
    const int ntiles = (slot < 4) ? 5 : 4;       // w = slot + i*64 < 260
    const int nchunks = 2 * ntiles;
    const int kbase0 = xcd * 260 + slot;

    // stage one K-chunk: 8 global_load_lds(16B) per thread (4 A + 4 B)
    #define STAGE(bufsel, bro, bco, kc)                                              \
        {                                                                            \
            _Pragma("unroll")                                                        \
            for (int i = 0; i < 4; ++i) {                                            \
                int o   = (i * 256 + tid) * 16;   /* linear LDS byte offset */       \
                int r   = o >> 7;                 /* row (128 B per row) */          \
                int cb  = o & 127;                                                   \
                int scb = cb ^ ((r & 7) << 4);    /* inverse-swizzled source */      \
                const u8* gA = f8 + (size_t)((bro) + r) * DDIM + (kc) + scb;         \
                __builtin_amdgcn_global_load_lds(                                    \
                    (const __attribute__((address_space(1))) void*)gA,               \
                    (__attribute__((address_space(3))) void*)(&lA[bufsel][0] + o),   \
                    16, 0, 0);                                                       \
                const u8* gB = f8 + (size_t)((bco) + r) * DDIM + (kc) + scb;         \
                __builtin_amdgcn_global_load_lds(                                    \
                    (const __attribute__((address_space(1))) void*)gB,               \
                    (__attribute__((address_space(3))) void*)(&lB[bufsel][0] + o),   \
                    16, 0, 0);                                                       \
            }                                                                        \
        }

    f32x4 acc[4][4];
    #pragma unroll
    for (int m = 0; m < 4; ++m)
        #pragma unroll
        for (int n = 0; n < 4; ++n)
            acc[m][n] = (f32x4){0.f, 0.f, 0.f, 0.f};

    int ti, tj, nti = 0, ntj = 0;
    decode_tile(kbase0, ti, tj);
    STAGE(0, ti * 128, tj * 128, 0);

    const int kb = (lane >> 4) << 5;   // this lane-group's 32 k-bytes start

    for (int c = 0; c < nchunks; ++c) {
        // ---- issue next chunk's stage, then wait for CURRENT chunk only ----
        if (c + 1 < nchunks) {
            if ((c + 1) & 1) {
                STAGE((c + 1) & 1, ti * 128, tj * 128, 128);     // 2nd half of cur tile
            } else {
                decode_tile(kbase0 + ((c + 1) >> 1) * 64, nti, ntj);
                STAGE((c + 1) & 1, nti * 128, ntj * 128, 0);     // next tile, 1st half
            }
            asm volatile("s_waitcnt vmcnt(8)" ::: "memory");     // chunk c done; c+1 in flight
        } else {
            asm volatile("s_waitcnt vmcnt(0)" ::: "memory");     // last chunk: full drain
        }
        __builtin_amdgcn_s_barrier();                            // buf[c&1] ready for all
        CFENCE;

        // ---- compute current chunk: 16 ds_read_b128 + 16 MX MFMAs ----
        const u8* bA = &lA[c & 1][0];
        const u8* bB = &lB[c & 1][0];
        i32x8 av[4], bv[4];
        #pragma unroll
        for (int m = 0; m < 4; ++m) {
            int rA = wr * 64 + m * 16 + (lane & 15);
            int sw = (rA & 7) << 4;
            const u8* p = bA + rA * 128;
            i32x4 lo = *(const i32x4*)(p + (kb ^ sw));
            i32x4 hi = *(const i32x4*)(p + ((kb + 16) ^ sw));
            av[m][0] = lo[0]; av[m][1] = lo[1]; av[m][2] = lo[2]; av[m][3] = lo[3];
            av[m][4] = hi[0]; av[m][5] = hi[1]; av[m][6] = hi[2]; av[m][7] = hi[3];
        }
        #pragma unroll
        for (int n = 0; n < 4; ++n) {
            int rB = wc * 64 + n * 16 + (lane & 15);
            int sw = (rB & 7) << 4;
            const u8* p = bB + rB * 128;
            i32x4 lo = *(const i32x4*)(p + (kb ^ sw));
            i32x4 hi = *(const i32x4*)(p + ((kb + 16) ^ sw));
            bv[n][0] = lo[0]; bv[n][1] = lo[1]; bv[n][2] = lo[2]; bv[n][3] = lo[3];
            bv[n][4] = hi[0]; bv[n][5] = hi[1]; bv[n][6] = hi[2]; bv[n][7] = hi[3];
        }
        #pragma unroll
        for (int m = 0; m < 4; ++m)
            #pragma unroll
            for (int n = 0; n < 4; ++n)
                acc[m][n] = __builtin_amdgcn_mfma_scale_f32_16x16x128_f8f6f4(
                    av[m], bv[n], acc[m][n],
                    0, 0,                 // cbsz=FP8(e4m3), blgp=FP8(e4m3)
                    0, 0x7f7f7f7f,        // A scale: x1
                    0, 0x7f7f7f7f);       // B scale: x1

        // ---- tile finished? epilogue + reset ----
        if (c & 1) {
            const int brow = ti * 128, bcol = tj * 128;
            // C layout: col = lane&15, row = (lane>>4)*4 + j (shape-determined)
            #pragma unroll
            for (int m = 0; m < 4; ++m)
                #pragma unroll
                for (int n = 0; n < 4; ++n)
                    #pragma unroll
                    for (int j = 0; j < 4; ++j)
                        acc[m][n][j] = __expf(acc[m][n][j]);

            float rs[4][4];
            #pragma unroll
            for (int m = 0; m < 4; ++m)
                #pragma unroll
                for (int j = 0; j < 4; ++j) {
                    float s = acc[m][0][j] + acc[m][1][j] + acc[m][2][j] + acc[m][3][j];
                    s += __shfl_xor(s, 1, 64);
                    s += __shfl_xor(s, 2, 64);
                    s += __shfl_xor(s, 4, 64);
                    s += __shfl_xor(s, 8, 64);
                    rs[m][j] = s;
                }

            if (ti == tj) {
                const bool diag = (wr == wc);       // batch blocks are 64-aligned
                if ((lane & 15) == 0) {
                    const int g = lane >> 4;
                    #pragma unroll
                    for (int m = 0; m < 4; ++m)
                        #pragma unroll
                        for (int j = 0; j < 4; ++j) {
                            int row = brow + wr * 64 + m * 16 + g * 4 + j;
                            float v = rs[m][j];
                            atomicAdd(&tot_acc[row], v);
                            if (diag) atomicAdd(&pos_acc[row], v);
                        }
                }
            } else {
                float cs[4];
                #pragma unroll
                for (int n = 0; n < 4; ++n) {
                    float s = 0.f;
                    #pragma unroll
                    for (int m = 0; m < 4; ++m)
                        #pragma unroll
                        for (int j = 0; j < 4; ++j) s += acc[m][n][j];
                    s += __shfl_xor(s, 16, 64);
                    s += __shfl_xor(s, 32, 64);
                    cs[n] = s;
                }
                if ((lane & 15) == 0) {
                    const int g = lane >> 4;
                    #pragma unroll
                    for (int m = 0; m < 4; ++m)
                        #pragma unroll
                        for (int j = 0; j < 4; ++j)
                            atomicAdd(&tot_acc[brow + wr * 64 + m * 16 + g * 4 + j], rs[m][j]);
                }
                if (lane < 16) {
                    #pragma unroll
                    for (int n = 0; n < 4; ++n)
                        atomicAdd(&tot_acc[bcol + wc * 64 + n * 16 + lane], cs[n]);
                }
            }
            // reset for next tile
            #pragma unroll
            for (int m = 0; m < 4; ++m)
                #pragma unroll
                for (int n = 0; n < 4; ++n)
                    acc[m][n] = (f32x4){0.f, 0.f, 0.f, 0.f};
            ti = nti; tj = ntj;
        }
        CFENCE;
        __builtin_amdgcn_s_barrier();   // all waves done reading buf[c&1]
        CFENCE;
    }
    #undef STAGE
}

// ---------------- Kernel 3: loss = mean(log(total) - log(pos)) ----------------
__global__ __launch_bounds__(1024) void loss_kernel(const float* __restrict__ tot,
                                                    const float* __restrict__ pos,
                                                    float* __restrict__ out) {
    __shared__ float red[16];
    int tid = threadIdx.x;
    float s = 0.f;
    for (int r = tid; r < NROWS; r += 1024)
        s += logf(tot[r]) - logf(pos[r]);
    #pragma unroll
    for (int m = 1; m < 64; m <<= 1) s += __shfl_xor(s, m, 64);
    if ((tid & 63) == 0) red[tid >> 6] = s;
    __syncthreads();
    if (tid == 0) {
        float t = 0.f;
        #pragma unroll
        for (int i = 0; i < 16; ++i) t += red[i];
        out[0] = t * (1.0f / (float)NROWS);
    }
}

extern "C" void kernel_launch(void* const* d_in, const int* in_sizes, int n_in,
                              void* d_out, int out_size, void* d_ws, size_t ws_size,
                              hipStream_t stream) {
    const float* feat = (const float*)d_in[0];
    u8*    f8   = (u8*)d_ws;                                    // 8192*256 = 2 MB
    float* tot  = (float*)((char*)d_ws + (size_t)NROWS * DDIM); // +2 MB
    float* pos  = tot + NROWS;
    norm_kernel<<<dim3(NROWS / 4), dim3(256), 0, stream>>>(feat, f8, tot);
    sim_kernel<<<dim3(GRID), dim3(256), 0, stream>>>(f8, tot, pos);
    loss_kernel<<<dim3(1), dim3(1024), 0, stream>>>(tot, pos, (float*)d_out);
}

// Round 10
// 90.953 us; speedup vs baseline: 2.6288x; 1.0016x over previous
//
#include <hip/hip_runtime.h>
#include <hip/hip_bf16.h>
#include <hip/hip_fp8.h>

typedef unsigned char u8;
typedef __attribute__((ext_vector_type(4))) float f32x4;
typedef __attribute__((ext_vector_type(4))) int   i32x4;
typedef __attribute__((ext_vector_type(8))) int   i32x8;

#define NROWS 8192   // B*N = 128*64
#define DDIM  256    // feature dim
#define NBLK  2080   // 64*65/2 triangular 128x128 tiles
#define GRID  512    // persistent blocks (2 per CU)

// ---------------- Kernel 1: L2-normalize rows, f32 -> fp8 e4m3 (+ zero accumulators) ----
__global__ __launch_bounds__(256) void norm_kernel(const float* __restrict__ in,
                                                   u8* __restrict__ out,
                                                   float* __restrict__ acc0) {
    int tid = threadIdx.x;
    if (blockIdx.x < 64) acc0[blockIdx.x * 256 + tid] = 0.f;  // zero tot+pos (16384 f32)
    int wave = tid >> 6, lane = tid & 63;
    int row = blockIdx.x * 4 + wave;                 // 2048 blocks * 4 rows
    float4 v = ((const float4*)(in + (size_t)row * DDIM))[lane];
    float ss = v.x * v.x + v.y * v.y + v.z * v.z + v.w * v.w;
    #pragma unroll
    for (int m = 1; m < 64; m <<= 1) ss += __shfl_xor(ss, m, 64);
    float sc = 1.0f / fmaxf(sqrtf(ss), 1e-12f);
    __hip_fp8_e4m3 q0(v.x * sc), q1(v.y * sc), q2(v.z * sc), q3(v.w * sc);
    unsigned pk = (unsigned)q0.__x | ((unsigned)q1.__x << 8) |
                  ((unsigned)q2.__x << 16) | ((unsigned)q3.__x << 24);
    ((unsigned*)out)[row * 64 + lane] = pk;          // 4 fp8 bytes per lane
}

// ---------------- Kernel 2: persistent fused Gram + exp + row/col-sum ----------------
// 512 persistent blocks of 512 THREADS (8 waves, 4x2 wave grid, 32x64 per-wave
// sub-tile) -> 16 waves/CU = 4 waves/SIMD at the same 64 KB LDS (2 blocks/CU).
// Block b owns tiles k = (b&7)*260 + (b>>3) + i*64 (XCD-chunked).
// Per tile: 2 K-chunks of 128 (fp8). LDS double-buffer (4 x 16 KB).
// Pipeline (T4 counted vmcnt): STAGE(c+1) [4 glds/thread]; s_waitcnt vmcnt(4)
// (chunk c ready, c+1 in flight); s_barrier; compute(c); s_barrier.
// MFMA: mfma_scale_f32_16x16x128_f8f6f4, unit scales (e8m0 0x7f).
// Swizzle (rule 21): linear LDS dest, inverse-swizzled source, XOR (r&7)<<4 on read.
__device__ inline void decode_tile(int k, int& ti, int& tj) {
    int a = (int)((sqrtf(8.f * (float)k + 1.f) - 1.f) * 0.5f);
    while ((a + 1) * (a + 2) / 2 <= k) ++a;
    while (a * (a + 1) / 2 > k) --a;
    ti = k - a * (a + 1) / 2;  // row tile
    tj = a;                    // col tile, ti <= tj
}

#define CFENCE asm volatile("" ::: "memory")

__global__ __launch_bounds__(512, 4) void sim_kernel(const u8* __restrict__ f8,
                                                     float* __restrict__ tot_acc,
                                                     float* __restrict__ pos_acc) {
    __shared__ u8 lA[2][128 * 128];   // 2 x 16 KB
    __shared__ u8 lB[2][128 * 128];   // 2 x 16 KB  (64 KB total)

    const int tid  = threadIdx.x;
    const int lane = tid & 63;
    const int wave = tid >> 6;        // 0..7
    const int wr = wave >> 1;         // 0..3 : rows wr*32 .. wr*32+31
    const int wc = wave & 1;          // 0..1 : cols wc*64 .. wc*64+63

    const int xcd  = blockIdx.x & 7;
    const int slot = blockIdx.x >> 3;            // 0..63
    const int ntiles = (slot < 4) ? 5 : 4;       // w = slot + i*64 < 260
    const int nchunks = 2 * ntiles;
    const int kbase0 = xcd * 260 + slot;

    // stage one K-chunk: 4 global_load_lds(16B) per thread (2 A + 2 B), 512 threads
    #define STAGE(bufsel, bro, bco, kc)                                              \
        {                                                                            \
            _Pragma("unroll")                                                        \
            for (int i = 0; i < 2; ++i) {                                            \
                int o   = (i * 512 + tid) * 16;   /* linear LDS byte offset */       \
                int r   = o >> 7;                 /* row (128 B per row) */          \
                int cb  = o & 127;                                                   \
                int scb = cb ^ ((r & 7) << 4);    /* inverse-swizzled source */      \
                const u8* gA = f8 + (size_t)((bro) + r) * DDIM + (kc) + scb;         \
                __builtin_amdgcn_global_load_lds(                                    \
                    (const __attribute__((address_space(1))) void*)gA,               \
                    (__attribute__((address_space(3))) void*)(&lA[bufsel][0] + o),   \
                    16, 0, 0);                                                       \
                const u8* gB = f8 + (size_t)((bco) + r) * DDIM + (kc) + scb;         \
                __builtin_amdgcn_global_load_lds(                                    \
                    (const __attribute__((address_space(1))) void*)gB,               \
                    (__attribute__((address_space(3))) void*)(&lB[bufsel][0] + o),   \
                    16, 0, 0);                                                       \
            }                                                                        \
        }

    f32x4 acc[2][4];
    #pragma unroll
    for (int m = 0; m < 2; ++m)
        #pragma unroll
        for (int n = 0; n < 4; ++n)
            acc[m][n] = (f32x4){0.f, 0.f, 0.f, 0.f};

    int ti, tj, nti = 0, ntj = 0;
    decode_tile(kbase0, ti, tj);
    STAGE(0, ti * 128, tj * 128, 0);

    const int kb = (lane >> 4) << 5;   // this lane-group's 32 k-bytes start

    for (int c = 0; c < nchunks; ++c) {
        // ---- issue next chunk's stage, then wait for CURRENT chunk only ----
        if (c + 1 < nchunks) {
            if ((c + 1) & 1) {
                STAGE((c + 1) & 1, ti * 128, tj * 128, 128);     // 2nd half of cur tile
            } else {
                decode_tile(kbase0 + ((c + 1) >> 1) * 64, nti, ntj);
                STAGE((c + 1) & 1, nti * 128, ntj * 128, 0);     // next tile, 1st half
            }
            asm volatile("s_waitcnt vmcnt(4)" ::: "memory");     // chunk c done; c+1 in flight
        } else {
            asm volatile("s_waitcnt vmcnt(0)" ::: "memory");     // last chunk: full drain
        }
        __builtin_amdgcn_s_barrier();                            // buf[c&1] ready for all
        CFENCE;

        // ---- compute current chunk: 12 ds_read_b128 + 8 MX MFMAs per wave ----
        const u8* bA = &lA[c & 1][0];
        const u8* bB = &lB[c & 1][0];
        i32x8 av[2], bv[4];
        #pragma unroll
        for (int m = 0; m < 2; ++m) {
            int rA = wr * 32 + m * 16 + (lane & 15);
            int sw = (rA & 7) << 4;
            const u8* p = bA + rA * 128;
            i32x4 lo = *(const i32x4*)(p + (kb ^ sw));
            i32x4 hi = *(const i32x4*)(p + ((kb + 16) ^ sw));
            av[m][0] = lo[0]; av[m][1] = lo[1]; av[m][2] = lo[2]; av[m][3] = lo[3];
            av[m][4] = hi[0]; av[m][5] = hi[1]; av[m][6] = hi[2]; av[m][7] = hi[3];
        }
        #pragma unroll
        for (int n = 0; n < 4; ++n) {
            int rB = wc * 64 + n * 16 + (lane & 15);
            int sw = (rB & 7) << 4;
            const u8* p = bB + rB * 128;
            i32x4 lo = *(const i32x4*)(p + (kb ^ sw));
            i32x4 hi = *(const i32x4*)(p + ((kb + 16) ^ sw));
            bv[n][0] = lo[0]; bv[n][1] = lo[1]; bv[n][2] = lo[2]; bv[n][3] = lo[3];
            bv[n][4] = hi[0]; bv[n][5] = hi[1]; bv[n][6] = hi[2]; bv[n][7] = hi[3];
        }
        #pragma unroll
        for (int m = 0; m < 2; ++m)
            #pragma unroll
            for (int n = 0; n < 4; ++n)
                acc[m][n] = __builtin_amdgcn_mfma_scale_f32_16x16x128_f8f6f4(
                    av[m], bv[n], acc[m][n],
                    0, 0,                 // cbsz=FP8(e4m3), blgp=FP8(e4m3)
                    0, 0x7f7f7f7f,        // A scale: x1
                    0, 0x7f7f7f7f);       // B scale: x1

        // ---- tile finished? epilogue + reset ----
        if (c & 1) {
            const int brow = ti * 128, bcol = tj * 128;
            // C layout: col = lane&15, row = (lane>>4)*4 + j (shape-determined)
            #pragma unroll
            for (int m = 0; m < 2; ++m)
                #pragma unroll
                for (int n = 0; n < 4; ++n)
                    #pragma unroll
                    for (int j = 0; j < 4; ++j)
                        acc[m][n][j] = __expf(acc[m][n][j]);

            float rs[2][4];
            #pragma unroll
            for (int m = 0; m < 2; ++m)
                #pragma unroll
                for (int j = 0; j < 4; ++j) {
                    float s = acc[m][0][j] + acc[m][1][j] + acc[m][2][j] + acc[m][3][j];
                    s += __shfl_xor(s, 1, 64);
                    s += __shfl_xor(s, 2, 64);
                    s += __shfl_xor(s, 4, 64);
                    s += __shfl_xor(s, 8, 64);
                    rs[m][j] = s;
                }

            if (ti == tj) {
                const bool diag = ((wr >> 1) == wc);   // batch blocks are 64-aligned
                if ((lane & 15) == 0) {
                    const int g = lane >> 4;
                    #pragma unroll
                    for (int m = 0; m < 2; ++m)
                        #pragma unroll
                        for (int j = 0; j < 4; ++j) {
                            int row = brow + wr * 32 + m * 16 + g * 4 + j;
                            float v = rs[m][j];
                            atomicAdd(&tot_acc[row], v);
                            if (diag) atomicAdd(&pos_acc[row], v);
                        }
                }
            } else {
                float cs[4];
                #pragma unroll
                for (int n = 0; n < 4; ++n) {
                    float s = 0.f;
                    #pragma unroll
                    for (int m = 0; m < 2; ++m)
                        #pragma unroll
                        for (int j = 0; j < 4; ++j) s += acc[m][n][j];
                    s += __shfl_xor(s, 16, 64);
                    s += __shfl_xor(s, 32, 64);
                    cs[n] = s;
                }
                if ((lane & 15) == 0) {
                    const int g = lane >> 4;
                    #pragma unroll
                    for (int m = 0; m < 2; ++m)
                        #pragma unroll
                        for (int j = 0; j < 4; ++j)
                            atomicAdd(&tot_acc[brow + wr * 32 + m * 16 + g * 4 + j], rs[m][j]);
                }
                if (lane < 16) {
                    #pragma unroll
                    for (int n = 0; n < 4; ++n)
                        atomicAdd(&tot_acc[bcol + wc * 64 + n * 16 + lane], cs[n]);
                }
            }
            // reset for next tile
            #pragma unroll
            for (int m = 0; m < 2; ++m)
                #pragma unroll
                for (int n = 0; n < 4; ++n)
                    acc[m][n] = (f32x4){0.f, 0.f, 0.f, 0.f};
            ti = nti; tj = ntj;
        }
        CFENCE;
        __builtin_amdgcn_s_barrier();   // all waves done reading buf[c&1]
        CFENCE;
    }
    #undef STAGE
}

// ---------------- Kernel 3: loss = mean(log(total) - log(pos)) ----------------
__global__ __launch_bounds__(1024) void loss_kernel(const float* __restrict__ tot,
                                                    const float* __restrict__ pos,
                                                    float* __restrict__ out) {
    __shared__ float red[16];
    int tid = threadIdx.x;
    float s = 0.f;
    for (int r = tid; r < NROWS; r += 1024)
        s += logf(tot[r]) - logf(pos[r]);
    #pragma unroll
    for (int m = 1; m < 64; m <<= 1) s += __shfl_xor(s, m, 64);
    if ((tid & 63) == 0) red[tid >> 6] = s;
    __syncthreads();
    if (tid == 0) {
        float t = 0.f;
        #pragma unroll
        for (int i = 0; i < 16; ++i) t += red[i];
        out[0] = t * (1.0f / (float)NROWS);
    }
}

extern "C" void kernel_launch(void* const* d_in, const int* in_sizes, int n_in,
                              void* d_out, int out_size, void* d_ws, size_t ws_size,
                              hipStream_t stream) {
    const float* feat = (const float*)d_in[0];
    u8*    f8   = (u8*)d_ws;                                    // 8192*256 = 2 MB
    float* tot  = (float*)((char*)d_ws + (size_t)NROWS * DDIM); // +2 MB
    float* pos  = tot + NROWS;
    norm_kernel<<<dim3(NROWS / 4), dim3(256), 0, stream>>>(feat, f8, tot);
    sim_kernel<<<dim3(GRID), dim3(512), 0, stream>>>(f8, tot, pos);
    loss_kernel<<<dim3(1), dim3(1024), 0, stream>>>(tot, pos, (float*)d_out);
}